// Round 1
// baseline (527.631 us; speedup 1.0000x reference)
//
#include <hip/hip_runtime.h>
#include <math.h>

#define NROWS 524288
constexpr float EPSW = 1e-8f;

// ---------------- workspace layout (float offsets) ----------------
constexpr int OFF_WVT     = 0;       // 64x64   WvT[d][j]
constexpr int OFF_WIHT_BG = 4096;    // 64x192  wihT[d][j]
constexpr int OFF_WHHT_BG = 16384;
constexpr int OFF_WIHT_FG = 28672;
constexpr int OFF_WHHT_FG = 40960;
constexpr int OFF_W1T_BG  = 53248;   // 64x128
constexpr int OFF_W2T_BG  = 61440;   // 128x64
constexpr int OFF_W1T_FG  = 69632;
constexpr int OFF_W2T_FG  = 77824;
constexpr int OFF_WQT_BG  = 86016;   // 64x64
constexpr int OFF_WQT_FG  = 90112;
constexpr int OFF_SLOTS   = 94208;   // 3x64 slot state
constexpr int OFF_QG      = 94400;   // 2 sets x 3 x 64 (qk*g)
constexpr int OFF_QS      = 94784;   // 2 sets x 6  (QG[3], QB[3])
constexpr int OFF_M       = 94800;   // 2 sets x 3 x 64 accumulators
constexpr int OFF_W       = 95184;   // 2 sets x 3
constexpr int OFF_CM      = 95190;   // 2 sets x 3
// total ~95196 floats = 381 KB of ws

__device__ __forceinline__ float wave_sum(float v) {
#pragma unroll
  for (int m = 1; m < 64; m <<= 1) v += __shfl_xor(v, m, 64);
  return v;
}

// ---------------- weight transpose ----------------
struct TJob { const float* src; int RC; int Cshift; int dstOff; };
struct TArgs { TJob j[11]; };

__global__ void transpose_k(TArgs a, float* __restrict__ ws) {
  TJob jb = a.j[blockIdx.x];
  const int C = 1 << jb.Cshift;
  const int R = jb.RC >> jb.Cshift;
  float* dst = ws + jb.dstOff;
  for (int e = threadIdx.x; e < jb.RC; e += blockDim.x) {
    int r = e >> jb.Cshift;
    int c = e & (C - 1);
    dst[c * R + r] = jb.src[e];
  }
}

// ---------------- q -> qk -> (qg, QG, QB) for one slot (one wave) ----------------
__device__ void emit_q(int lane, float snew,
                       const float* __restrict__ lnq_g, const float* __restrict__ lnq_b,
                       const float* __restrict__ WqT, const float* __restrict__ Wk,
                       const float* __restrict__ g_in, const float* __restrict__ b_in,
                       float* scratch /*64, wave-local*/,
                       float* __restrict__ qg_out /*64*/, float* __restrict__ qs_out /*6*/, int s)
{
  float mean = wave_sum(snew) * (1.0f / 64.0f);
  float d = snew - mean;
  float var = wave_sum(d * d) * (1.0f / 64.0f);
  float lns = d * rsqrtf(var + 1e-5f) * lnq_g[lane] + lnq_b[lane];
  scratch[lane] = lns;
  float q = 0.f;
#pragma unroll
  for (int dd = 0; dd < 64; ++dd) q = fmaf(scratch[dd], WqT[dd * 64 + lane], q);
  q *= 0.125f;               // SLOT_DIM^-0.5
  scratch[lane] = q;         // same-wave program order: all reads above precede this write
  float qk = 0.f;
#pragma unroll
  for (int j = 0; j < 64; ++j) qk = fmaf(scratch[j], Wk[j * 64 + lane], qk);
  float qgv = qk * g_in[lane];
  qg_out[lane] = qgv;
  float QG = wave_sum(qgv);
  float QB = wave_sum(qk * b_in[lane]);
  if (lane == 0) { qs_out[s] = QG; qs_out[3 + s] = QB; }
}

// ---------------- init: slots, iter-0 q, zero accumulators ----------------
__global__ void init_k(const float* __restrict__ noise_fg, const float* __restrict__ noise_bg,
                       const float* __restrict__ g_in, const float* __restrict__ b_in,
                       const float* __restrict__ mu_fg, const float* __restrict__ logsig_fg,
                       const float* __restrict__ mu_bg, const float* __restrict__ logsig_bg,
                       const float* __restrict__ lnq_fg_g, const float* __restrict__ lnq_fg_b,
                       const float* __restrict__ lnq_bg_g, const float* __restrict__ lnq_bg_b,
                       const float* __restrict__ Wk, float* __restrict__ ws)
{
  __shared__ float scratch[64];
  const int lane = threadIdx.x;
#pragma unroll
  for (int i = 0; i < 6; ++i) ws[OFF_M + i * 64 + lane] = 0.f;
  if (lane < 12) ws[OFF_W + lane] = 0.f;

  float s0 = mu_bg[lane] + __expf(logsig_bg[lane]) * noise_bg[lane];
  float s1 = mu_fg[lane] + __expf(logsig_fg[lane]) * noise_fg[lane];
  float s2 = mu_fg[lane] + __expf(logsig_fg[lane]) * noise_fg[64 + lane];
  ws[OFF_SLOTS + lane] = s0;
  ws[OFF_SLOTS + 64 + lane] = s1;
  ws[OFF_SLOTS + 128 + lane] = s2;

  emit_q(lane, s0, lnq_bg_g, lnq_bg_b, ws + OFF_WQT_BG, Wk, g_in, b_in, scratch,
         ws + OFF_QG + 0, ws + OFF_QS, 0);
  emit_q(lane, s1, lnq_fg_g, lnq_fg_b, ws + OFF_WQT_FG, Wk, g_in, b_in, scratch,
         ws + OFF_QG + 64, ws + OFF_QS, 1);
  emit_q(lane, s2, lnq_fg_g, lnq_fg_b, ws + OFF_WQT_FG, Wk, g_in, b_in, scratch,
         ws + OFF_QG + 128, ws + OFF_QS, 2);
}

// ---------------- the streaming attention pass ----------------
// 3 waves/block; each wave owns a 64-row chunk at a time; no barriers in the loop.
template <int WRITE_OUT>
__launch_bounds__(192) __global__ void attn_pass_k(
    const float* __restrict__ x,
    const float* __restrict__ qg,   // 3x64
    const float* __restrict__ qs,   // QG[3], QB[3]
    float* __restrict__ M_out,      // 3x64
    float* __restrict__ W_out,      // 3
    float* __restrict__ CM_out,     // 3
    float* __restrict__ attn_out)   // d_out+192 (s*N+n) or null
{
  __shared__ float  lx[3][64 * 65];   // pad-65: conflict-free row & column access
  __shared__ float4 lc[3][64];        // per-row c0,c1,c2 ; reused as reduce buffer
  __shared__ float4 lqg4[48];         // qg staged: s*16 + i
  __shared__ float  lsc[3][8];
  const int tid = threadIdx.x;
  const int wid = tid >> 6, lane = tid & 63;
  if (tid < 48) lqg4[tid] = ((const float4*)qg)[tid];
  __syncthreads();
  const float QG0 = qs[0], QG1 = qs[1], QG2 = qs[2];
  const float QB0 = qs[3], QB1 = qs[4], QB2 = qs[5];

  float accM0 = 0, accM1 = 0, accM2 = 0;
  float accW0 = 0, accW1 = 0, accW2 = 0;
  float accC0 = 0, accC1 = 0, accC2 = 0;
  float* lxw = lx[wid];
  const int nw = gridDim.x * 3;

  for (int chunk = blockIdx.x * 3 + wid; chunk < (NROWS / 64); chunk += nw) {
    const int n0 = chunk << 6;
    const float4* xp = (const float4*)(x + (size_t)n0 * 64);
    // stage 64 rows (coalesced) into padded LDS
#pragma unroll
    for (int i = 0; i < 16; ++i) {
      float4 v = xp[i * 64 + lane];
      int f = (i * 64 + lane) << 2;
      float* p = &lxw[(f >> 6) * 65 + (f & 63)];
      p[0] = v.x; p[1] = v.y; p[2] = v.z; p[3] = v.w;
    }
    // phase A: row-in-lane — stats + 3 dots with qg, softmax
    const float* rowp = &lxw[lane * 65];
    float sum = 0.f, ssq = 0.f, da0 = 0.f, da1 = 0.f, da2 = 0.f;
#pragma unroll
    for (int i = 0; i < 16; ++i) {
      float x0 = rowp[4 * i], x1 = rowp[4 * i + 1], x2 = rowp[4 * i + 2], x3 = rowp[4 * i + 3];
      float4 q0 = lqg4[i], q1 = lqg4[16 + i], q2 = lqg4[32 + i];
      sum += (x0 + x1) + (x2 + x3);
      ssq = fmaf(x0, x0, fmaf(x1, x1, fmaf(x2, x2, fmaf(x3, x3, ssq))));
      da0 = fmaf(x0, q0.x, fmaf(x1, q0.y, fmaf(x2, q0.z, fmaf(x3, q0.w, da0))));
      da1 = fmaf(x0, q1.x, fmaf(x1, q1.y, fmaf(x2, q1.z, fmaf(x3, q1.w, da1))));
      da2 = fmaf(x0, q2.x, fmaf(x1, q2.y, fmaf(x2, q2.z, fmaf(x3, q2.w, da2))));
    }
    float mean = sum * 0.015625f;
    float var  = fmaf(ssq, 0.015625f, -mean * mean);
    float rs   = rsqrtf(var + 1e-5f);
    float l0 = fmaf(rs, da0 - mean * QG0, QB0);
    float l1 = fmaf(rs, da1 - mean * QG1, QB1);
    float l2 = fmaf(rs, da2 - mean * QG2, QB2);
    float mx = fmaxf(l0, fmaxf(l1, l2));
    float e0 = __expf(l0 - mx), e1 = __expf(l1 - mx), e2 = __expf(l2 - mx);
    float inv = 1.0f / (e0 + e1 + e2);
    float a0 = e0 * inv, a1 = e1 * inv, a2 = e2 * inv;
    if (WRITE_OUT) {
      attn_out[0 * NROWS + n0 + lane] = a0;
      attn_out[1 * NROWS + n0 + lane] = a1;
      attn_out[2 * NROWS + n0 + lane] = a2;
    }
    float aw0 = a0 + EPSW, aw1 = a1 + EPSW, aw2 = a2 + EPSW;
    accW0 += aw0; accW1 += aw1; accW2 += aw2;
    float c0 = aw0 * rs, c1 = aw1 * rs, c2 = aw2 * rs;
    accC0 = fmaf(c0, mean, accC0);
    accC1 = fmaf(c1, mean, accC1);
    accC2 = fmaf(c2, mean, accC2);
    lc[wid][lane] = make_float4(c0, c1, c2, 0.f);
    // phase B: lane-per-d weighted column accumulate (raw x still in LDS)
#pragma unroll
    for (int r = 0; r < 64; ++r) {
      float4 c = lc[wid][r];
      float xv = lxw[r * 65 + lane];
      accM0 = fmaf(c.x, xv, accM0);
      accM1 = fmaf(c.y, xv, accM1);
      accM2 = fmaf(c.z, xv, accM2);
    }
  }

  // block reduce + atomics
  accW0 = wave_sum(accW0); accW1 = wave_sum(accW1); accW2 = wave_sum(accW2);
  accC0 = wave_sum(accC0); accC1 = wave_sum(accC1); accC2 = wave_sum(accC2);
  if (lane == 0) {
    lsc[wid][0] = accW0; lsc[wid][1] = accW1; lsc[wid][2] = accW2;
    lsc[wid][3] = accC0; lsc[wid][4] = accC1; lsc[wid][5] = accC2;
  }
  __syncthreads();                     // all waves done with lc
  float* red = (float*)lc;             // 768 floats available, need 576
  red[wid * 192 + lane]        = accM0;
  red[wid * 192 + 64 + lane]   = accM1;
  red[wid * 192 + 128 + lane]  = accM2;
  __syncthreads();
  if (tid < 192) atomicAdd(&M_out[tid], red[tid] + red[192 + tid] + red[384 + tid]);
  if (tid < 6) {
    float v = lsc[0][tid] + lsc[1][tid] + lsc[2][tid];
    if (tid < 3) atomicAdd(&W_out[tid], v);
    else         atomicAdd(&CM_out[tid - 3], v);
  }
}

// ---------------- slot update: upd -> GRU -> MLP -> (q for next iter | write slots) ----------------
__launch_bounds__(192) __global__ void update_k(
    const float* __restrict__ g_in, const float* __restrict__ b_in,
    const float* __restrict__ gbg_bih, const float* __restrict__ gbg_bhh,
    const float* __restrict__ gfg_bih, const float* __restrict__ gfg_bhh,
    const float* __restrict__ mbg_ln_g, const float* __restrict__ mbg_ln_b,
    const float* __restrict__ mfg_ln_g, const float* __restrict__ mfg_ln_b,
    const float* __restrict__ mbg_b1, const float* __restrict__ mbg_b2,
    const float* __restrict__ mfg_b1, const float* __restrict__ mfg_b2,
    const float* __restrict__ lnq_fg_g, const float* __restrict__ lnq_fg_b,
    const float* __restrict__ lnq_bg_g, const float* __restrict__ lnq_bg_b,
    const float* __restrict__ Wk,
    float* __restrict__ ws, int set_in, int last, float* __restrict__ out_slots)
{
  __shared__ float sA[3][64], sU[3][64], sH[3][64], sHid[3][128];
  const int tid = threadIdx.x, wid = tid >> 6, lane = tid & 63;
  const bool bg = (wid == 0);
  const float* wihT = ws + (bg ? OFF_WIHT_BG : OFF_WIHT_FG);
  const float* whhT = ws + (bg ? OFF_WHHT_BG : OFF_WHHT_FG);
  const float* w1T  = ws + (bg ? OFF_W1T_BG : OFF_W1T_FG);
  const float* w2T  = ws + (bg ? OFF_W2T_BG : OFF_W2T_FG);
  const float* WqT  = ws + (bg ? OFF_WQT_BG : OFF_WQT_FG);
  const float* bih = bg ? gbg_bih : gfg_bih;
  const float* bhh = bg ? gbg_bhh : gfg_bhh;
  const float* mlg = bg ? mbg_ln_g : mfg_ln_g;
  const float* mlb = bg ? mbg_ln_b : mfg_ln_b;
  const float* b1  = bg ? mbg_b1 : mfg_b1;
  const float* b2  = bg ? mbg_b2 : mfg_b2;
  const float* lqg = bg ? lnq_bg_g : lnq_fg_g;
  const float* lqb = bg ? lnq_bg_b : lnq_fg_b;

  const float Wsum = ws[OFF_W + set_in * 3 + wid];
  const float CM   = ws[OFF_CM + set_in * 3 + wid];
  const float Mv   = ws[OFF_M + set_in * 192 + wid * 64 + lane];
  float m = g_in[lane] * (Mv - CM) + b_in[lane] * Wsum;   // m_s[d] = sum_n aw*xn
  sA[wid][lane] = m;
  __syncthreads();

  const float* WvT = ws + OFF_WVT;
  float upd = 0.f;
#pragma unroll
  for (int d = 0; d < 64; ++d) upd = fmaf(sA[wid][d], WvT[d * 64 + lane], upd);
  upd /= Wsum;

  float h = ws[OFF_SLOTS + wid * 64 + lane];
  sU[wid][lane] = upd; sH[wid][lane] = h;
  __syncthreads();

  float gi0 = bih[lane], gi1 = bih[64 + lane], gi2 = bih[128 + lane];
  float gh0 = bhh[lane], gh1 = bhh[64 + lane], gh2 = bhh[128 + lane];
#pragma unroll
  for (int d = 0; d < 64; ++d) {
    float u = sU[wid][d], hh = sH[wid][d];
    const float* wi = &wihT[d * 192];
    const float* wh = &whhT[d * 192];
    gi0 = fmaf(u, wi[lane], gi0);
    gi1 = fmaf(u, wi[64 + lane], gi1);
    gi2 = fmaf(u, wi[128 + lane], gi2);
    gh0 = fmaf(hh, wh[lane], gh0);
    gh1 = fmaf(hh, wh[64 + lane], gh1);
    gh2 = fmaf(hh, wh[128 + lane], gh2);
  }
  float r  = 1.f / (1.f + __expf(-(gi0 + gh0)));
  float z  = 1.f / (1.f + __expf(-(gi1 + gh1)));
  float nn = tanhf(fmaf(r, gh2, gi2));
  float hp = (1.f - z) * nn + z * h;

  // MLP with residual
  float mean = wave_sum(hp) * (1.f / 64.f);
  float dv = hp - mean;
  float var = wave_sum(dv * dv) * (1.f / 64.f);
  float lnh = dv * rsqrtf(var + 1e-5f) * mlg[lane] + mlb[lane];
  __syncthreads();
  sA[wid][lane] = lnh;
  __syncthreads();
  float h1a = b1[lane], h1b = b1[64 + lane];
#pragma unroll
  for (int d = 0; d < 64; ++d) {
    float t = sA[wid][d];
    h1a = fmaf(t, w1T[d * 128 + lane], h1a);
    h1b = fmaf(t, w1T[d * 128 + 64 + lane], h1b);
  }
  h1a = fmaxf(h1a, 0.f); h1b = fmaxf(h1b, 0.f);
  sHid[wid][lane] = h1a; sHid[wid][64 + lane] = h1b;
  __syncthreads();
  float o = b2[lane];
#pragma unroll
  for (int j = 0; j < 128; ++j) o = fmaf(sHid[wid][j], w2T[j * 64 + lane], o);
  float snew = hp + o;
  ws[OFF_SLOTS + wid * 64 + lane] = snew;

  if (last) {
    out_slots[wid * 64 + lane] = snew;
  } else {
    int so = set_in ^ 1;
    emit_q(lane, snew, lqg, lqb, WqT, Wk, g_in, b_in, sA[wid],
           ws + OFF_QG + so * 192 + wid * 64, ws + OFF_QS + so * 6, wid);
  }
}

// ---------------- launcher ----------------
extern "C" void kernel_launch(void* const* d_in, const int* in_sizes, int n_in,
                              void* d_out, int out_size, void* d_ws, size_t ws_size,
                              hipStream_t stream)
{
  (void)in_sizes; (void)n_in; (void)out_size; (void)ws_size;
  const float* x         = (const float*)d_in[0];
  const float* noise_fg  = (const float*)d_in[1];
  const float* noise_bg  = (const float*)d_in[2];
  const float* ln_in_g   = (const float*)d_in[3];
  const float* ln_in_b   = (const float*)d_in[4];
  const float* mu_fg     = (const float*)d_in[5];
  const float* logsig_fg = (const float*)d_in[6];
  const float* mu_bg     = (const float*)d_in[7];
  const float* logsig_bg = (const float*)d_in[8];
  const float* Wk        = (const float*)d_in[9];
  const float* Wv        = (const float*)d_in[10];
  const float* lnq_fg_g  = (const float*)d_in[11];
  const float* lnq_fg_b  = (const float*)d_in[12];
  const float* Wq_fg     = (const float*)d_in[13];
  const float* lnq_bg_g  = (const float*)d_in[14];
  const float* lnq_bg_b  = (const float*)d_in[15];
  const float* Wq_bg     = (const float*)d_in[16];
  const float* gfg_wih   = (const float*)d_in[17];
  const float* gfg_whh   = (const float*)d_in[18];
  const float* gfg_bih   = (const float*)d_in[19];
  const float* gfg_bhh   = (const float*)d_in[20];
  const float* gbg_wih   = (const float*)d_in[21];
  const float* gbg_whh   = (const float*)d_in[22];
  const float* gbg_bih   = (const float*)d_in[23];
  const float* gbg_bhh   = (const float*)d_in[24];
  const float* mfg_ln_g  = (const float*)d_in[25];
  const float* mfg_ln_b  = (const float*)d_in[26];
  const float* mfg_w1    = (const float*)d_in[27];
  const float* mfg_b1    = (const float*)d_in[28];
  const float* mfg_w2    = (const float*)d_in[29];
  const float* mfg_b2    = (const float*)d_in[30];
  const float* mbg_ln_g  = (const float*)d_in[31];
  const float* mbg_ln_b  = (const float*)d_in[32];
  const float* mbg_w1    = (const float*)d_in[33];
  const float* mbg_b1    = (const float*)d_in[34];
  const float* mbg_w2    = (const float*)d_in[35];
  const float* mbg_b2    = (const float*)d_in[36];

  float* ws  = (float*)d_ws;
  float* out = (float*)d_out;

  TArgs ta;
  ta.j[0]  = {Wv,      64 * 64,  6, OFF_WVT};
  ta.j[1]  = {gbg_wih, 192 * 64, 6, OFF_WIHT_BG};
  ta.j[2]  = {gbg_whh, 192 * 64, 6, OFF_WHHT_BG};
  ta.j[3]  = {gfg_wih, 192 * 64, 6, OFF_WIHT_FG};
  ta.j[4]  = {gfg_whh, 192 * 64, 6, OFF_WHHT_FG};
  ta.j[5]  = {mbg_w1,  128 * 64, 6, OFF_W1T_BG};
  ta.j[6]  = {mbg_w2,  64 * 128, 7, OFF_W2T_BG};
  ta.j[7]  = {mfg_w1,  128 * 64, 6, OFF_W1T_FG};
  ta.j[8]  = {mfg_w2,  64 * 128, 7, OFF_W2T_FG};
  ta.j[9]  = {Wq_bg,   64 * 64,  6, OFF_WQT_BG};
  ta.j[10] = {Wq_fg,   64 * 64,  6, OFF_WQT_FG};
  transpose_k<<<11, 256, 0, stream>>>(ta, ws);

  init_k<<<1, 64, 0, stream>>>(noise_fg, noise_bg, ln_in_g, ln_in_b,
                               mu_fg, logsig_fg, mu_bg, logsig_bg,
                               lnq_fg_g, lnq_fg_b, lnq_bg_g, lnq_bg_b, Wk, ws);

  // iteration 0
  attn_pass_k<0><<<768, 192, 0, stream>>>(x, ws + OFF_QG, ws + OFF_QS,
                                          ws + OFF_M, ws + OFF_W, ws + OFF_CM, nullptr);
  update_k<<<1, 192, 0, stream>>>(ln_in_g, ln_in_b, gbg_bih, gbg_bhh, gfg_bih, gfg_bhh,
                                  mbg_ln_g, mbg_ln_b, mfg_ln_g, mfg_ln_b,
                                  mbg_b1, mbg_b2, mfg_b1, mfg_b2,
                                  lnq_fg_g, lnq_fg_b, lnq_bg_g, lnq_bg_b, Wk,
                                  ws, 0, 0, nullptr);
  // iteration 1 (writes attn.T)
  attn_pass_k<1><<<768, 192, 0, stream>>>(x, ws + OFF_QG + 192, ws + OFF_QS + 6,
                                          ws + OFF_M + 192, ws + OFF_W + 3, ws + OFF_CM + 3,
                                          out + 192);
  update_k<<<1, 192, 0, stream>>>(ln_in_g, ln_in_b, gbg_bih, gbg_bhh, gfg_bih, gfg_bhh,
                                  mbg_ln_g, mbg_ln_b, mfg_ln_g, mfg_ln_b,
                                  mbg_b1, mbg_b2, mfg_b1, mfg_b2,
                                  lnq_fg_g, lnq_fg_b, lnq_bg_g, lnq_bg_b, Wk,
                                  ws, 1, 1, out);
}